// Round 7
// baseline (446.230 us; speedup 1.0000x reference)
//
#include <hip/hip_runtime.h>
#include <hip/hip_bf16.h>
#include <stdint.h>

typedef __attribute__((ext_vector_type(8))) short bf16x8;
typedef __attribute__((ext_vector_type(4))) float f32x4;
typedef __attribute__((ext_vector_type(4))) unsigned short us4;
typedef __attribute__((ext_vector_type(8))) unsigned short us8;

__device__ __forceinline__ unsigned short f2bf(float f) {
  union { float f; unsigned int u; } v; v.f = f;
  unsigned int u = v.u;
  return (unsigned short)((u + 0x7FFFu + ((u >> 16) & 1u)) >> 16);
}
__device__ __forceinline__ float bf2f(unsigned short h) {
  union { unsigned int u; float f; } v; v.u = ((unsigned int)h) << 16;
  return v.f;
}

// async global->LDS, 16B per lane; LDS dest = wave-uniform base + lane*16
__device__ __forceinline__ void gload16(const unsigned short* g, unsigned short* l) {
  __builtin_amdgcn_global_load_lds(
      (const __attribute__((address_space(1))) unsigned int*)g,
      (__attribute__((address_space(3))) unsigned int*)l, 16, 0, 0);
}

// ---------------------------------------------------------------------------
// 256x256 NT GEMM, BK=32, 512 threads (8 waves, 2M x 4N), 3-buffer LDS
// pipeline with depth-2 prefetch and counted vmcnt (never 0 in main loop).
// C[M,N] = A[M,K] * Bt[N,K]^T, A/B bf16 row-major (lda=ldb=K).
// Per-wave C: 128x64 (8 m-frags x 4 n-frags) -> 12 ds_read_b128 : 32 MFMA.
// LDS per buffer: A[256][32] + B[256][32] bf16 = 32 KB; 3 buffers = 96 KB.
// Swizzle: k-slot s (4 slots of 8 elems) stored at s ^ (row&3); staging
// pre-swizzles the GLOBAL source so linear gload_lds writes land swizzled
// (rule 21: same involution on source and read). Conflict-free (uniform
// 8 words/bank per b128).
// Schedule per K-step t: {vmcnt(4); barrier; issue T(t+2)->free buf;
// 12 ds_read; setprio(1); 32 MFMA; setprio(0)}.  Safety: buffer written by
// T(t+2) was last read at t-1; all t-1 ds_reads completed before their MFMAs
// (lgkm), which precede the barrier -> no WAR race.
// EPI 0: bf16 C row-major          EPI 1: scores (thr+exp, bf16 e + partials)
// EPI 2: bf16 C transposed per batch (v-proj)   EPI 3: bf16 acc*inv[row] (PV)
// ---------------------------------------------------------------------------
template <int EPI>
__global__ __launch_bounds__(512, 1)
void gemm9(const unsigned short* __restrict__ Ap, const unsigned short* __restrict__ Btp,
           void* __restrict__ Cp, float* __restrict__ extra,
           int M, int N, int K, int nbm, int nbn,
           long long sA, long long sB, long long sC)
{
  __shared__ unsigned short ls[3 * 16384];   // 96 KiB: [buf][A 8192 | B 8192]
  __shared__ float srow[256][4];

  const int tid = threadIdx.x;
  const int lane = tid & 63;
  const int wid = tid >> 6;
  const int bb = blockIdx.y;
  const int bm = blockIdx.x % nbm, bn = blockIdx.x / nbm;
  const int row0 = bm * 256, col0 = bn * 256;

  const unsigned short* Ab = Ap + (long long)bb * sA;
  const unsigned short* Bb = Btp + (long long)bb * sB;

  // staging: wave w stages rows [w*32, w*32+32) of A and of B (cols of C).
  // per gload: 16 rows (lane>>2), k-slot pre-swizzled: (lane&3)^((lane>>2)&3)
  const int stgrow = wid * 32 + (lane >> 2);
  const int sslot = (lane & 3) ^ ((lane >> 2) & 3);
  const unsigned short* Asrc = Ab + (long long)(row0 + stgrow) * K + sslot * 8;
  const unsigned short* Bsrc = Bb + (long long)(col0 + stgrow) * K + sslot * 8;

  const int warow = (wid >> 2) * 128 + (lane & 15);   // A row base (per mf +16)
  const int wbcol = (wid & 3) * 64 + (lane & 15);     // B col base (per nf +16)
  const int rslot = ((lane >> 4) ^ (lane & 3)) * 8;   // swizzled k-slot (elems)

#define ISSUE(KT, CB) do { \
    unsigned short* _la = ls + (CB) * 16384 + wid * 1024; \
    unsigned short* _lb = _la + 8192; \
    const long long _ko = (long long)(KT) * 32; \
    gload16(Asrc + _ko, _la); \
    gload16(Asrc + 16ll * K + _ko, _la + 512); \
    gload16(Bsrc + _ko, _lb); \
    gload16(Bsrc + 16ll * K + _ko, _lb + 512); \
  } while (0)

  f32x4 acc[8][4];
#pragma unroll
  for (int m = 0; m < 8; ++m)
#pragma unroll
    for (int n = 0; n < 4; ++n) {
      f32x4 z = {0.f, 0.f, 0.f, 0.f};
      acc[m][n] = z;
    }

  const int NT = K >> 5;
  // prologue: T0 -> buf0, T1 -> buf1 (8 loads in flight)
  ISSUE(0, 0);
  ISSUE(1, 1);

  int c0 = 0, c1 = 1, c2 = 2;
  for (int t = 0; t < NT; ++t) {
    if (t + 1 < NT) asm volatile("s_waitcnt vmcnt(4)" ::: "memory");
    else            asm volatile("s_waitcnt vmcnt(0)" ::: "memory");
    __builtin_amdgcn_s_barrier();
    __builtin_amdgcn_sched_barrier(0);
    if (t + 2 < NT) ISSUE(t + 2, c2);
    {
      const unsigned short* _A = ls + c0 * 16384;
      const unsigned short* _B = _A + 8192;
      bf16x8 af[8], bfr[4];
#pragma unroll
      for (int mf = 0; mf < 8; ++mf)
        af[mf] = *(const bf16x8*)&_A[(warow + mf * 16) * 32 + rslot];
#pragma unroll
      for (int nf = 0; nf < 4; ++nf)
        bfr[nf] = *(const bf16x8*)&_B[(wbcol + nf * 16) * 32 + rslot];
      __builtin_amdgcn_s_setprio(1);
#pragma unroll
      for (int mf = 0; mf < 8; ++mf)
#pragma unroll
        for (int nf = 0; nf < 4; ++nf)
          acc[mf][nf] = __builtin_amdgcn_mfma_f32_16x16x32_bf16(
              af[mf], bfr[nf], acc[mf][nf], 0, 0, 0);
      __builtin_amdgcn_s_setprio(0);
    }
    int tmp = c0; c0 = c1; c1 = c2; c2 = tmp;
  }
#undef ISSUE

  // ---------------- epilogues ----------------
  if (EPI == 0 || EPI == 3) {
    unsigned short* C = (unsigned short*)Cp + (long long)bb * sC;
    const float* inv = (EPI == 3) ? (extra + (long long)bb * 2048) : nullptr;
#pragma unroll
    for (int mf = 0; mf < 8; ++mf)
#pragma unroll
      for (int nf = 0; nf < 4; ++nf)
#pragma unroll
        for (int i = 0; i < 4; ++i) {
          int gr = row0 + (wid >> 2) * 128 + mf * 16 + (lane >> 4) * 4 + i;
          int gc = col0 + (wid & 3) * 64 + nf * 16 + (lane & 15);
          float x = acc[mf][nf][i];
          if (EPI == 3) x *= inv[gr];
          C[(long long)gr * N + gc] = f2bf(x);
        }
  } else if (EPI == 2) {
    unsigned short* C = (unsigned short*)Cp;
#pragma unroll
    for (int mf = 0; mf < 8; ++mf)
#pragma unroll
      for (int nf = 0; nf < 4; ++nf) {
        int gr = row0 + (wid >> 2) * 128 + mf * 16 + (lane >> 4) * 4;
        int gc = col0 + (wid & 3) * 64 + nf * 16 + (lane & 15);
        int bb2 = gr >> 11, grb = gr & 2047;
        us4 o;
        o[0] = f2bf(acc[mf][nf][0]); o[1] = f2bf(acc[mf][nf][1]);
        o[2] = f2bf(acc[mf][nf][2]); o[3] = f2bf(acc[mf][nf][3]);
        *(us4*)&C[(long long)bb2 * sC + (long long)gc * 2048 + grb] = o;
      }
  } else {   // EPI 1: scores
    unsigned short* C = (unsigned short*)Cp + (long long)bb * sC;
    float rs[8][4];
#pragma unroll
    for (int mf = 0; mf < 8; ++mf)
#pragma unroll
      for (int i = 0; i < 4; ++i) rs[mf][i] = 0.f;
#pragma unroll
    for (int mf = 0; mf < 8; ++mf)
#pragma unroll
      for (int nf = 0; nf < 4; ++nf)
#pragma unroll
        for (int i = 0; i < 4; ++i) {
          int gr = row0 + (wid >> 2) * 128 + mf * 16 + (lane >> 4) * 4 + i;
          int gc = col0 + (wid & 3) * 64 + nf * 16 + (lane & 15);
          float s = acc[mf][nf][i] * 0.03125f;   // 1/sqrt(1024)
          s = (s < 0.9f) ? 0.f : s;              // threshold BEFORE softmax
          float e = __expf(s);                   // bounded: no max-subtraction
          C[(long long)gr * N + gc] = f2bf(e);
          rs[mf][i] += e;
        }
#pragma unroll
    for (int mf = 0; mf < 8; ++mf)
#pragma unroll
      for (int i = 0; i < 4; ++i) {
        float vv = rs[mf][i];
        vv += __shfl_xor(vv, 1); vv += __shfl_xor(vv, 2);
        vv += __shfl_xor(vv, 4); vv += __shfl_xor(vv, 8);
        if ((lane & 15) == 0)
          srow[(wid >> 2) * 128 + mf * 16 + (lane >> 4) * 4 + i][wid & 3] = vv;
      }
    __syncthreads();
    if (tid < 256) {
      int gr = row0 + tid;
      extra[((long long)bb * M + gr) * nbn + bn] =
          srow[tid][0] + srow[tid][1] + srow[tid][2] + srow[tid][3];
    }
  }
}

// ---------------------------------------------------------------------------
// q,k,v fp32 -> bf16, one pass (8 elem/thread each)
// ---------------------------------------------------------------------------
__global__ __launch_bounds__(256)
void cvt3(const float* __restrict__ a, const float* __restrict__ b,
          const float* __restrict__ c, unsigned short* __restrict__ oa,
          unsigned short* __restrict__ ob, unsigned short* __restrict__ oc) {
  const long long i = ((long long)blockIdx.x * 256 + threadIdx.x) * 8;
#pragma unroll
  for (int p = 0; p < 3; ++p) {
    const float* src = (p == 0) ? a : (p == 1) ? b : c;
    unsigned short* dst = (p == 0) ? oa : (p == 1) ? ob : oc;
    f32x4 x0 = *(const f32x4*)(src + i);
    f32x4 x1 = *(const f32x4*)(src + i + 4);
    us8 o;
    o[0] = f2bf(x0[0]); o[1] = f2bf(x0[1]); o[2] = f2bf(x0[2]); o[3] = f2bf(x0[3]);
    o[4] = f2bf(x1[0]); o[5] = f2bf(x1[1]); o[6] = f2bf(x1[2]); o[7] = f2bf(x1[3]);
    *(us8*)(dst + i) = o;
  }
}

// ---------------------------------------------------------------------------
// W [1024][1024] fp32 -> WT [1024][1024] bf16 (transposed)
// ---------------------------------------------------------------------------
__global__ __launch_bounds__(256)
void wtrans(const float* __restrict__ W, unsigned short* __restrict__ WT) {
  __shared__ float t[32][33];
  const int bi = blockIdx.x, bj = blockIdx.y;
  const int c = threadIdx.x & 31;
  const int r0 = threadIdx.x >> 5;
#pragma unroll
  for (int j = 0; j < 4; ++j) {
    int r = r0 + j * 8;
    t[r][c] = W[(long long)(bi * 32 + r) * 1024 + bj * 32 + c];
  }
  __syncthreads();
#pragma unroll
  for (int j = 0; j < 4; ++j) {
    int r = r0 + j * 8;
    WT[(long long)(bj * 32 + r) * 1024 + bi * 32 + c] = f2bf(t[c][r]);
  }
}

// ---------------------------------------------------------------------------
// attn f32 output + inv_dens from bf16 exp-scores and partials (width 8)
// ---------------------------------------------------------------------------
__global__ __launch_bounds__(256)
void attn_norm(const unsigned short* __restrict__ e, const float* __restrict__ partials,
               float* __restrict__ attn, float* __restrict__ inv_dens) {
  const long long row = blockIdx.x;
  const int tid = threadIdx.x;
  __shared__ float sden;
  if (tid < 64) {
    float v = (tid < 8) ? partials[row * 8 + tid] : 0.f;
    v += __shfl_xor(v, 1); v += __shfl_xor(v, 2); v += __shfl_xor(v, 4);
    if (tid == 0) sden = v;
  }
  __syncthreads();
  const float inv = 1.0f / sden;
  if (tid == 0) inv_dens[row] = inv;
  us8 x = *(const us8*)(e + row * 2048 + tid * 8);
  f32x4 y0, y1;
#pragma unroll
  for (int i = 0; i < 4; ++i) { y0[i] = bf2f(x[i]) * inv; y1[i] = bf2f(x[i + 4]) * inv; }
  *(f32x4*)(attn + row * 2048 + tid * 8) = y0;
  *(f32x4*)(attn + row * 2048 + tid * 8 + 4) = y1;
}

// ---------------------------------------------------------------------------
// out(f32) = LayerNorm(fc(bf16) + q(f32)) * gamma + beta   (row = 1024)
// ---------------------------------------------------------------------------
__global__ __launch_bounds__(256)
void ln_kernel(const unsigned short* __restrict__ fc, const float* __restrict__ q,
               const float* __restrict__ gamma, const float* __restrict__ beta,
               float* __restrict__ out) {
  const long long row = blockIdx.x;
  const int tid = threadIdx.x;
  __shared__ float sb1[4], sb2[4];
  us4 hv = *(const us4*)(fc + row * 1024 + tid * 4);
  f32x4 qv = *(const f32x4*)(q + row * 1024 + tid * 4);
  float x0 = bf2f(hv[0]) + qv[0];
  float x1 = bf2f(hv[1]) + qv[1];
  float x2 = bf2f(hv[2]) + qv[2];
  float x3 = bf2f(hv[3]) + qv[3];
  float s = x0 + x1 + x2 + x3;
#pragma unroll
  for (int m = 1; m < 64; m <<= 1) s += __shfl_xor(s, m);
  if ((tid & 63) == 0) sb1[tid >> 6] = s;
  __syncthreads();
  const float mean = (sb1[0] + sb1[1] + sb1[2] + sb1[3]) * (1.0f / 1024.0f);
  float d0 = x0 - mean, d1 = x1 - mean, d2 = x2 - mean, d3 = x3 - mean;
  float vs = d0 * d0 + d1 * d1 + d2 * d2 + d3 * d3;
#pragma unroll
  for (int m = 1; m < 64; m <<= 1) vs += __shfl_xor(vs, m);
  if ((tid & 63) == 0) sb2[tid >> 6] = vs;
  __syncthreads();
  const float var = (sb2[0] + sb2[1] + sb2[2] + sb2[3]) * (1.0f / 1024.0f);
  const float r = rsqrtf(var + 1e-6f);
  f32x4 g = *(const f32x4*)(gamma + tid * 4);
  f32x4 bt = *(const f32x4*)(beta + tid * 4);
  f32x4 o;
  o[0] = d0 * r * g[0] + bt[0];
  o[1] = d1 * r * g[1] + bt[1];
  o[2] = d2 * r * g[2] + bt[2];
  o[3] = d3 * r * g[3] + bt[3];
  *(f32x4*)(out + row * 1024 + tid * 4) = o;
}

// ---------------------------------------------------------------------------
// d_out = [ out0 f32 64MB | attn f32 128MB ].  Scratch timeline as round 5/6.
// ws: W*T @0/2/4/6M; partials@8M ([16384][8]); inv_dens@10M; e bf16 @11M
// (64MB); fc reuses e after PV.
// ---------------------------------------------------------------------------
extern "C" void kernel_launch(void* const* d_in, const int* in_sizes, int n_in,
                              void* d_out, int out_size, void* d_ws, size_t ws_size,
                              hipStream_t stream) {
  const float* q    = (const float*)d_in[0];
  const float* k    = (const float*)d_in[1];
  const float* v    = (const float*)d_in[2];
  const float* Wq   = (const float*)d_in[3];
  const float* Wk   = (const float*)d_in[4];
  const float* Wv   = (const float*)d_in[5];
  const float* Wfc  = (const float*)d_in[6];
  const float* gamma = (const float*)d_in[7];
  const float* beta  = (const float*)d_in[8];

  float* out0 = (float*)d_out;
  float* attn = out0 + (long long)8 * 2048 * 1024;

  char* ao = (char*)attn;
  unsigned short* qb = (unsigned short*)(ao);
  unsigned short* kb = (unsigned short*)(ao + (32ll << 20));
  unsigned short* vb = (unsigned short*)(ao + (64ll << 20));
  unsigned short* qh = (unsigned short*)(ao + (96ll << 20));
  unsigned short* kh = (unsigned short*)(ao);
  unsigned short* vhT     = (unsigned short*)d_out;
  unsigned short* out_mid = (unsigned short*)((char*)d_out + (32ll << 20));

  char* ws = (char*)d_ws;
  unsigned short* WqT  = (unsigned short*)(ws);
  unsigned short* WkT  = (unsigned short*)(ws + (2ll  << 20));
  unsigned short* WvT  = (unsigned short*)(ws + (4ll  << 20));
  unsigned short* WfcT = (unsigned short*)(ws + (6ll  << 20));
  float* partials      = (float*)(ws + (8ll  << 20));            // [16384][8]
  float* inv_dens      = (float*)(ws + (10ll << 20));            // [16384]
  unsigned short* e    = (unsigned short*)(ws + (11ll << 20));   // 64MB
  unsigned short* fc   = e;

  // 1. conversions
  cvt3<<<dim3(8192), 256, 0, stream>>>(q, k, v, qb, kb, vb);
  wtrans<<<dim3(32, 32), 256, 0, stream>>>(Wq, WqT);
  wtrans<<<dim3(32, 32), 256, 0, stream>>>(Wk, WkT);
  wtrans<<<dim3(32, 32), 256, 0, stream>>>(Wv, WvT);
  wtrans<<<dim3(32, 32), 256, 0, stream>>>(Wfc, WfcT);

  // 2. projections (M=16384 batch-folded, 256x256 tiles: nbm=64, nbn=4)
  gemm9<0><<<dim3(256, 1), 512, 0, stream>>>(qb, WqT, qh, nullptr,
      16384, 1024, 1024, 64, 4, 0, 0, 0);
  gemm9<0><<<dim3(256, 1), 512, 0, stream>>>(kb, WkT, kh, nullptr,
      16384, 1024, 1024, 64, 4, 0, 0, 0);
  gemm9<2><<<dim3(256, 1), 512, 0, stream>>>(vb, WvT, vhT, nullptr,
      16384, 1024, 1024, 64, 4, 0, 0, 1024ll * 2048);   // vhT[b][d][s]

  // 3. scores: e = exp(thresh(qh kh^T / 32)) bf16 + partial row sums (w=8)
  gemm9<1><<<dim3(64, 8), 512, 0, stream>>>(qh, kh, e, partials,
      2048, 2048, 1024, 8, 8, 2048ll * 1024, 2048ll * 1024, 2048ll * 2048);

  // 4. attn(f32) = e/den; inv_dens
  attn_norm<<<dim3(16384), 256, 0, stream>>>(e, partials, attn, inv_dens);

  // 5. PV: out_mid = (e @ vh) * inv_den[row]   (nbm=8, nbn=4)
  gemm9<3><<<dim3(32, 8), 512, 0, stream>>>(e, vhT, out_mid, inv_dens,
      2048, 1024, 2048, 8, 4, 2048ll * 2048, 1024ll * 2048, 2048ll * 1024);

  // 6. FC: fc = out_mid @ Wfc
  gemm9<0><<<dim3(256, 1), 512, 0, stream>>>(out_mid, WfcT, fc, nullptr,
      16384, 1024, 1024, 64, 4, 0, 0, 0);

  // 7. out0 = LN(fc + q)
  ln_kernel<<<dim3(16384), 256, 0, stream>>>(fc, q, gamma, beta, out0);
}

// Round 8
// 414.061 us; speedup vs baseline: 1.0777x; 1.0777x over previous
//
#include <hip/hip_runtime.h>
#include <hip/hip_bf16.h>
#include <stdint.h>

typedef __attribute__((ext_vector_type(8))) short bf16x8;
typedef __attribute__((ext_vector_type(4))) float f32x4;
typedef __attribute__((ext_vector_type(4))) unsigned short us4;
typedef __attribute__((ext_vector_type(8))) unsigned short us8;

__device__ __forceinline__ unsigned short f2bf(float f) {
  union { float f; unsigned int u; } v; v.f = f;
  unsigned int u = v.u;
  return (unsigned short)((u + 0x7FFFu + ((u >> 16) & 1u)) >> 16);
}
__device__ __forceinline__ float bf2f(unsigned short h) {
  union { unsigned int u; float f; } v; v.u = ((unsigned int)h) << 16;
  return v.f;
}

// async global->LDS, 16B per lane; LDS dest = wave-uniform base + lane*16
__device__ __forceinline__ void gload16(const unsigned short* g, unsigned short* l) {
  __builtin_amdgcn_global_load_lds(
      (const __attribute__((address_space(1))) unsigned int*)g,
      (__attribute__((address_space(3))) unsigned int*)l, 16, 0, 0);
}

// ---------------------------------------------------------------------------
// PROVEN round-5 structure (420us): 128x128 NT GEMM, BK=64, 256 threads,
// global_load_lds w16 with pre-swizzled source (slot s -> s^(r&7), bank period
// = 1 row at 128B rows -> conflict-free, measured 0), __syncthreads drain,
// multi-block/CU overlap (m97-class, ~945 TF effective).
// C[M,N] = A[M,K] * Bt[N,K]^T, A/B bf16 row-major (lda=ldb=K).
// EPI 0: bf16 C row-major             (projections, FC)
// EPI 1: s=acc/32; thr 0.9; e=exp(s); bf16 e + per-(row,bn) partial row sums
// EPI 2: bf16 C transposed Ct[b][col][row], batch = gr>>11   (v-projection)
// EPI 3: bf16 (acc * inv_dens[bb*2048+gr])                   (PV)
// ---------------------------------------------------------------------------
template <int EPI>
__global__ __launch_bounds__(256, 2)
void gemm_nt(const unsigned short* __restrict__ Ap, const unsigned short* __restrict__ Btp,
             void* __restrict__ Cp, float* __restrict__ extra,
             int M, int N, int K, int nbm,
             long long sA, long long sB, long long sC)
{
  const int tid = threadIdx.x;
  const int lane = tid & 63;
  const int wid = tid >> 6;
  const int wr = wid >> 1, wc = wid & 1;
  const int bb = blockIdx.y;
  const int bm = blockIdx.x % nbm, bn = blockIdx.x / nbm;
  const int row0 = bm * 128, col0 = bn * 128;

  __shared__ unsigned short lsA[128 * 64];   // [row][8 slots of 16B], swizzled
  __shared__ unsigned short lsB[128 * 64];
  __shared__ float srow2[128][2];

  const unsigned short* Ab = Ap + (long long)bb * sA;
  const unsigned short* Bb = Btp + (long long)bb * sB;

  // staging geometry: wave w covers tile rows [w*32, w*32+32); 4 issues of
  // 64 lanes x 16B each (8 rows/issue). Lane's global 16B-slot is constant:
  // s = (lane&7) ^ (lane>>3)  (since r&7 == lane>>3 for every issue).
  const int srow = wid * 32 + (lane >> 3);
  const int sslot = (lane & 7) ^ (lane >> 3);
  const unsigned short* Asrc = Ab + (long long)(row0 + srow) * K + sslot * 8;
  const unsigned short* Bsrc = Bb + (long long)(col0 + srow) * K + sslot * 8;
  unsigned short* ldsA0 = &lsA[wid * 2048];   // 256 slots * 8 elem
  unsigned short* ldsB0 = &lsB[wid * 2048];

  f32x4 acc[4][4];
#pragma unroll
  for (int i = 0; i < 4; ++i)
#pragma unroll
    for (int j = 0; j < 4; ++j) {
      f32x4 z = {0.f, 0.f, 0.f, 0.f};
      acc[i][j] = z;
    }

  for (int k0 = 0; k0 < K; k0 += 64) {
    __syncthreads();
#pragma unroll
    for (int it = 0; it < 4; ++it) {
      gload16(Asrc + (long long)it * 8 * K + k0, ldsA0 + it * 512);
      gload16(Bsrc + (long long)it * 8 * K + k0, ldsB0 + it * 512);
    }
    __syncthreads();   // compiler drains vmcnt(0) before barrier
#pragma unroll
    for (int kk = 0; kk < 2; ++kk) {
      int kslot = kk * 4 + (lane >> 4);
      bf16x8 af[4], bfg[4];
#pragma unroll
      for (int mf = 0; mf < 4; ++mf) {
        int rl = wr * 64 + mf * 16 + (lane & 15);
        af[mf] = *(const bf16x8*)&lsA[rl * 64 + ((kslot ^ (rl & 7)) * 8)];
      }
#pragma unroll
      for (int nf = 0; nf < 4; ++nf) {
        int cl = wc * 64 + nf * 16 + (lane & 15);
        bfg[nf] = *(const bf16x8*)&lsB[cl * 64 + ((kslot ^ (cl & 7)) * 8)];
      }
#pragma unroll
      for (int mf = 0; mf < 4; ++mf)
#pragma unroll
        for (int nf = 0; nf < 4; ++nf)
          acc[mf][nf] = __builtin_amdgcn_mfma_f32_16x16x32_bf16(af[mf], bfg[nf], acc[mf][nf], 0, 0, 0);
    }
  }

  if (EPI == 0) {
    unsigned short* C = (unsigned short*)Cp + (long long)bb * sC;
#pragma unroll
    for (int mf = 0; mf < 4; ++mf)
#pragma unroll
      for (int nf = 0; nf < 4; ++nf)
#pragma unroll
        for (int i = 0; i < 4; ++i) {
          int gr = row0 + wr * 64 + mf * 16 + (lane >> 4) * 4 + i;
          int gc = col0 + wc * 64 + nf * 16 + (lane & 15);
          C[(long long)gr * N + gc] = f2bf(acc[mf][nf][i]);
        }
  } else if (EPI == 2) {
    unsigned short* C = (unsigned short*)Cp;
#pragma unroll
    for (int mf = 0; mf < 4; ++mf)
#pragma unroll
      for (int nf = 0; nf < 4; ++nf) {
        int gr = row0 + wr * 64 + mf * 16 + (lane >> 4) * 4;  // rows gr..gr+3
        int gc = col0 + wc * 64 + nf * 16 + (lane & 15);
        int bb2 = gr >> 11, grb = gr & 2047;
        us4 o;
        o[0] = f2bf(acc[mf][nf][0]); o[1] = f2bf(acc[mf][nf][1]);
        o[2] = f2bf(acc[mf][nf][2]); o[3] = f2bf(acc[mf][nf][3]);
        *(us4*)&C[(long long)bb2 * sC + (long long)gc * 2048 + grb] = o;
      }
  } else if (EPI == 3) {
    unsigned short* C = (unsigned short*)Cp + (long long)bb * sC;
    const float* inv = extra + (long long)bb * 2048;
#pragma unroll
    for (int mf = 0; mf < 4; ++mf)
#pragma unroll
      for (int nf = 0; nf < 4; ++nf)
#pragma unroll
        for (int i = 0; i < 4; ++i) {
          int gr = row0 + wr * 64 + mf * 16 + (lane >> 4) * 4 + i;
          int gc = col0 + wc * 64 + nf * 16 + (lane & 15);
          C[(long long)gr * N + gc] = f2bf(acc[mf][nf][i] * inv[gr]);
        }
  } else {   // EPI 1: scores
    unsigned short* C = (unsigned short*)Cp + (long long)bb * sC;
    float rs[4][4];
#pragma unroll
    for (int mf = 0; mf < 4; ++mf)
#pragma unroll
      for (int i = 0; i < 4; ++i) rs[mf][i] = 0.f;
#pragma unroll
    for (int mf = 0; mf < 4; ++mf)
#pragma unroll
      for (int nf = 0; nf < 4; ++nf)
#pragma unroll
        for (int i = 0; i < 4; ++i) {
          int gr = row0 + wr * 64 + mf * 16 + (lane >> 4) * 4 + i;
          int gc = col0 + wc * 64 + nf * 16 + (lane & 15);
          float s = acc[mf][nf][i] * 0.03125f;   // 1/sqrt(1024)
          s = (s < 0.9f) ? 0.f : s;              // hard threshold BEFORE softmax
          float e = __expf(s);                   // bounded by ~e^6: no max-sub
          C[(long long)gr * N + gc] = f2bf(e);
          rs[mf][i] += e;
        }
#pragma unroll
    for (int mf = 0; mf < 4; ++mf)
#pragma unroll
      for (int i = 0; i < 4; ++i) {
        float vv = rs[mf][i];
        vv += __shfl_xor(vv, 1); vv += __shfl_xor(vv, 2);
        vv += __shfl_xor(vv, 4); vv += __shfl_xor(vv, 8);
        if ((lane & 15) == 0)
          srow2[wr * 64 + mf * 16 + (lane >> 4) * 4 + i][wc] = vv;
      }
    __syncthreads();
    if (tid < 128) {
      int gr = row0 + tid;
      extra[((long long)bb * M + gr) * 16 + bn] = srow2[tid][0] + srow2[tid][1];
    }
  }
}

// ---------------------------------------------------------------------------
// q,k,v fp32 -> bf16, one pass (8 elem/thread each)
// ---------------------------------------------------------------------------
__global__ __launch_bounds__(256)
void cvt3(const float* __restrict__ a, const float* __restrict__ b,
          const float* __restrict__ c, unsigned short* __restrict__ oa,
          unsigned short* __restrict__ ob, unsigned short* __restrict__ oc) {
  const long long i = ((long long)blockIdx.x * 256 + threadIdx.x) * 8;
#pragma unroll
  for (int p = 0; p < 3; ++p) {
    const float* src = (p == 0) ? a : (p == 1) ? b : c;
    unsigned short* dst = (p == 0) ? oa : (p == 1) ? ob : oc;
    f32x4 x0 = *(const f32x4*)(src + i);
    f32x4 x1 = *(const f32x4*)(src + i + 4);
    us8 o;
    o[0] = f2bf(x0[0]); o[1] = f2bf(x0[1]); o[2] = f2bf(x0[2]); o[3] = f2bf(x0[3]);
    o[4] = f2bf(x1[0]); o[5] = f2bf(x1[1]); o[6] = f2bf(x1[2]); o[7] = f2bf(x1[3]);
    *(us8*)(dst + i) = o;
  }
}

// ---------------------------------------------------------------------------
// 4 weight transposes in one launch: W[1024][1024] f32 -> WT bf16 transposed.
// blockIdx.z selects the (W, WT) pair.
// ---------------------------------------------------------------------------
__global__ __launch_bounds__(256)
void wtrans4(const float* __restrict__ W0, const float* __restrict__ W1,
             const float* __restrict__ W2, const float* __restrict__ W3,
             unsigned short* __restrict__ T0, unsigned short* __restrict__ T1,
             unsigned short* __restrict__ T2, unsigned short* __restrict__ T3) {
  __shared__ float t[32][33];
  const int z = blockIdx.z;
  const float* W = (z == 0) ? W0 : (z == 1) ? W1 : (z == 2) ? W2 : W3;
  unsigned short* WT = (z == 0) ? T0 : (z == 1) ? T1 : (z == 2) ? T2 : T3;
  const int bi = blockIdx.x, bj = blockIdx.y;
  const int c = threadIdx.x & 31;
  const int r0 = threadIdx.x >> 5;
#pragma unroll
  for (int j = 0; j < 4; ++j) {
    int r = r0 + j * 8;
    t[r][c] = W[(long long)(bi * 32 + r) * 1024 + bj * 32 + c];
  }
  __syncthreads();
#pragma unroll
  for (int j = 0; j < 4; ++j) {
    int r = r0 + j * 8;
    WT[(long long)(bj * 32 + r) * 1024 + bi * 32 + c] = f2bf(t[c][r]);
  }
}

// ---------------------------------------------------------------------------
// attn f32 output + inv_dens from bf16 exp-scores and partials (width 16)
// ---------------------------------------------------------------------------
__global__ __launch_bounds__(256)
void attn_norm(const unsigned short* __restrict__ e, const float* __restrict__ partials,
               float* __restrict__ attn, float* __restrict__ inv_dens) {
  const long long row = blockIdx.x;
  const int tid = threadIdx.x;
  __shared__ float sden;
  if (tid < 64) {
    float v = (tid < 16) ? partials[row * 16 + tid] : 0.f;
    v += __shfl_xor(v, 1); v += __shfl_xor(v, 2);
    v += __shfl_xor(v, 4); v += __shfl_xor(v, 8);
    if (tid == 0) sden = v;
  }
  __syncthreads();
  const float inv = 1.0f / sden;
  if (tid == 0) inv_dens[row] = inv;
  us8 x = *(const us8*)(e + row * 2048 + tid * 8);
  f32x4 y0, y1;
#pragma unroll
  for (int i = 0; i < 4; ++i) { y0[i] = bf2f(x[i]) * inv; y1[i] = bf2f(x[i + 4]) * inv; }
  *(f32x4*)(attn + row * 2048 + tid * 8) = y0;
  *(f32x4*)(attn + row * 2048 + tid * 8 + 4) = y1;
}

// ---------------------------------------------------------------------------
// out(f32) = LayerNorm(fc(bf16) + q(f32)) * gamma + beta   (row = 1024)
// ---------------------------------------------------------------------------
__global__ __launch_bounds__(256)
void ln_kernel(const unsigned short* __restrict__ fc, const float* __restrict__ q,
               const float* __restrict__ gamma, const float* __restrict__ beta,
               float* __restrict__ out) {
  const long long row = blockIdx.x;
  const int tid = threadIdx.x;
  __shared__ float sb1[4], sb2[4];
  us4 hv = *(const us4*)(fc + row * 1024 + tid * 4);
  f32x4 qv = *(const f32x4*)(q + row * 1024 + tid * 4);
  float x0 = bf2f(hv[0]) + qv[0];
  float x1 = bf2f(hv[1]) + qv[1];
  float x2 = bf2f(hv[2]) + qv[2];
  float x3 = bf2f(hv[3]) + qv[3];
  float s = x0 + x1 + x2 + x3;
#pragma unroll
  for (int m = 1; m < 64; m <<= 1) s += __shfl_xor(s, m);
  if ((tid & 63) == 0) sb1[tid >> 6] = s;
  __syncthreads();
  const float mean = (sb1[0] + sb1[1] + sb1[2] + sb1[3]) * (1.0f / 1024.0f);
  float d0 = x0 - mean, d1 = x1 - mean, d2 = x2 - mean, d3 = x3 - mean;
  float vs = d0 * d0 + d1 * d1 + d2 * d2 + d3 * d3;
#pragma unroll
  for (int m = 1; m < 64; m <<= 1) vs += __shfl_xor(vs, m);
  if ((tid & 63) == 0) sb2[tid >> 6] = vs;
  __syncthreads();
  const float var = (sb2[0] + sb2[1] + sb2[2] + sb2[3]) * (1.0f / 1024.0f);
  const float r = rsqrtf(var + 1e-6f);
  f32x4 g = *(const f32x4*)(gamma + tid * 4);
  f32x4 bt = *(const f32x4*)(beta + tid * 4);
  f32x4 o;
  o[0] = d0 * r * g[0] + bt[0];
  o[1] = d1 * r * g[1] + bt[1];
  o[2] = d2 * r * g[2] + bt[2];
  o[3] = d3 * r * g[3] + bt[3];
  *(f32x4*)(out + row * 1024 + tid * 4) = o;
}

// ---------------------------------------------------------------------------
// d_out = [ out0 f32 64MB | attn f32 128MB ].  Scratch timeline:
//   attn region: qb@+0, kb@+32M, vb@+64M (cvt) -> qh@+96M (proj-q) ->
//                kh@+0 (proj-k, qb dead) -> attn f32 overwrites all (norm)
//   out0 region: vhT@+0, out_mid@+32M; ln overwrites last.
// ws (~75MB): W*T @0/2/4/6M; partials@8M ([16384][16]); inv_dens@10M;
//   e bf16 @11M (64MB); fc reuses e's first 32MB after PV consumed e.
// ---------------------------------------------------------------------------
extern "C" void kernel_launch(void* const* d_in, const int* in_sizes, int n_in,
                              void* d_out, int out_size, void* d_ws, size_t ws_size,
                              hipStream_t stream) {
  const float* q    = (const float*)d_in[0];
  const float* k    = (const float*)d_in[1];
  const float* v    = (const float*)d_in[2];
  const float* Wq   = (const float*)d_in[3];
  const float* Wk   = (const float*)d_in[4];
  const float* Wv   = (const float*)d_in[5];
  const float* Wfc  = (const float*)d_in[6];
  const float* gamma = (const float*)d_in[7];
  const float* beta  = (const float*)d_in[8];

  float* out0 = (float*)d_out;
  float* attn = out0 + (long long)8 * 2048 * 1024;

  char* ao = (char*)attn;
  unsigned short* qb = (unsigned short*)(ao);
  unsigned short* kb = (unsigned short*)(ao + (32ll << 20));
  unsigned short* vb = (unsigned short*)(ao + (64ll << 20));
  unsigned short* qh = (unsigned short*)(ao + (96ll << 20));
  unsigned short* kh = (unsigned short*)(ao);
  unsigned short* vhT     = (unsigned short*)d_out;
  unsigned short* out_mid = (unsigned short*)((char*)d_out + (32ll << 20));

  char* ws = (char*)d_ws;
  unsigned short* WqT  = (unsigned short*)(ws);
  unsigned short* WkT  = (unsigned short*)(ws + (2ll  << 20));
  unsigned short* WvT  = (unsigned short*)(ws + (4ll  << 20));
  unsigned short* WfcT = (unsigned short*)(ws + (6ll  << 20));
  float* partials      = (float*)(ws + (8ll  << 20));            // [16384][16]
  float* inv_dens      = (float*)(ws + (10ll << 20));            // [16384]
  unsigned short* e    = (unsigned short*)(ws + (11ll << 20));   // 64MB
  unsigned short* fc   = e;

  // 1. conversions (wtrans fused into one launch)
  cvt3<<<dim3(8192), 256, 0, stream>>>(q, k, v, qb, kb, vb);
  wtrans4<<<dim3(32, 32, 4), 256, 0, stream>>>(Wq, Wk, Wv, Wfc, WqT, WkT, WvT, WfcT);

  // 2. projections (batch folded into M=16384)
  gemm_nt<0><<<dim3(1024, 1), 256, 0, stream>>>(qb, WqT, qh, nullptr,
      16384, 1024, 1024, 128, 0, 0, 0);
  gemm_nt<0><<<dim3(1024, 1), 256, 0, stream>>>(kb, WkT, kh, nullptr,
      16384, 1024, 1024, 128, 0, 0, 0);
  gemm_nt<2><<<dim3(1024, 1), 256, 0, stream>>>(vb, WvT, vhT, nullptr,
      16384, 1024, 1024, 128, 0, 0, 1024ll * 2048);   // vhT[b][d][s]

  // 3. scores: e = exp(thresh(qh kh^T / 32)) bf16 + partial row sums
  gemm_nt<1><<<dim3(256, 8), 256, 0, stream>>>(qh, kh, e, partials,
      2048, 2048, 1024, 16, 2048ll * 1024, 2048ll * 1024, 2048ll * 2048);

  // 4. attn(f32) = e/den; inv_dens
  attn_norm<<<dim3(16384), 256, 0, stream>>>(e, partials, attn, inv_dens);

  // 5. PV: out_mid = (e @ vh) * inv_den[row]
  gemm_nt<3><<<dim3(128, 8), 256, 0, stream>>>(e, vhT, out_mid, inv_dens,
      2048, 1024, 2048, 16, 2048ll * 2048, 1024ll * 2048, 2048ll * 1024);

  // 6. FC: fc = out_mid @ Wfc
  gemm_nt<0><<<dim3(1024, 1), 256, 0, stream>>>(out_mid, WfcT, fc, nullptr,
      16384, 1024, 1024, 128, 0, 0, 0);

  // 7. out0 = LN(fc + q)
  ln_kernel<<<dim3(16384), 256, 0, stream>>>(fc, q, gamma, beta, out0);
}

// Round 9
// 411.639 us; speedup vs baseline: 1.0840x; 1.0059x over previous
//
#include <hip/hip_runtime.h>
#include <hip/hip_bf16.h>
#include <stdint.h>

typedef __attribute__((ext_vector_type(8))) short bf16x8;
typedef __attribute__((ext_vector_type(4))) float f32x4;
typedef __attribute__((ext_vector_type(4))) unsigned short us4;
typedef __attribute__((ext_vector_type(8))) unsigned short us8;

__device__ __forceinline__ unsigned short f2bf(float f) {
  union { float f; unsigned int u; } v; v.f = f;
  unsigned int u = v.u;
  return (unsigned short)((u + 0x7FFFu + ((u >> 16) & 1u)) >> 16);
}
__device__ __forceinline__ float bf2f(unsigned short h) {
  union { unsigned int u; float f; } v; v.u = ((unsigned int)h) << 16;
  return v.f;
}

// async global->LDS, 16B per lane; LDS dest = wave-uniform base + lane*16
__device__ __forceinline__ void gload16(const unsigned short* g, unsigned short* l) {
  __builtin_amdgcn_global_load_lds(
      (const __attribute__((address_space(1))) unsigned int*)g,
      (__attribute__((address_space(3))) unsigned int*)l, 16, 0, 0);
}

// ---------------------------------------------------------------------------
// 256x256 NT GEMM, BK=64, 512 threads (8 waves, 2M x 4N), double-buffered
// 128KiB LDS, minimum-2-phase pipeline (T3-min from the catalog):
//   per K-tile: vmcnt(0); s_barrier; sched_barrier;
//               STAGE(t+1 -> other buf); ds_read + 64 MFMA (setprio).
// The stage issued at tile t flies for the whole of tile t's compute before
// its drain at tile t+1's top -> HBM latency hidden (round-5's zero-flight
// drain was the exposed cost). Stage-after-barrier is race-free: all waves'
// tile-(t-1) ds_reads retired (lgkm) before reaching tile t's barrier.
// Slabs [256][64] bf16, 8 slots of 16B, slot' = slot ^ (row&7) (involution;
// measured 0-conflict in r5/6/8); staging pre-swizzles the GLOBAL source so
// linear gload_lds writes land swizzled (rule 21).
// Per wave: C = 128x64 (mf 0..7, nf 0..3); per tile 24 ds_read : 64 MFMA.
// EPI 0: bf16 C row-major          EPI 1: scores (thr+exp, bf16 e + partials)
// EPI 2: bf16 C transposed per batch (v-proj)   EPI 3: bf16 acc*inv[row] (PV)
// (epilogue geometry identical to round-7's correctness-verified kernel)
// ---------------------------------------------------------------------------
template <int EPI>
__global__ __launch_bounds__(512, 2)
void gemm2p(const unsigned short* __restrict__ Ap, const unsigned short* __restrict__ Btp,
            void* __restrict__ Cp, float* __restrict__ extra,
            int M, int N, int K, int nbm, int nbn,
            long long sA, long long sB, long long sC)
{
  __shared__ unsigned short ls[65536];   // 128 KiB: [buf 32768][A 16384 | B 16384]
  __shared__ float srow[256][4];

  const int tid = threadIdx.x;
  const int lane = tid & 63;
  const int wid = tid >> 6;
  const int bb = blockIdx.y;
  const int bm = blockIdx.x % nbm, bn = blockIdx.x / nbm;
  const int row0 = bm * 256, col0 = bn * 256;

  const unsigned short* Ab = Ap + (long long)bb * sA;
  const unsigned short* Bb = Btp + (long long)bb * sB;

  // staging: thread covers row tid>>3 of each 64-row chunk; global 16B-slot
  // pre-swizzled: (tid&7) ^ ((tid>>3)&7)  (row&7 == (tid>>3)&7 every chunk)
  const int srw = tid >> 3;
  const int ssl = (tid & 7) ^ ((tid >> 3) & 7);
  const unsigned short* Asrc = Ab + (long long)(row0 + srw) * K + ssl * 8;
  const unsigned short* Bsrc = Bb + (long long)(col0 + srw) * K + ssl * 8;

#define STAGE(KT, BUF) do { \
    unsigned short* _la = ls + (BUF) * 32768 + wid * 512; \
    unsigned short* _lb = _la + 16384; \
    const long long _ko = (long long)(KT) * 64; \
    gload16(Asrc + _ko,             _la); \
    gload16(Asrc + 64ll * K + _ko,  _la + 4096); \
    gload16(Asrc + 128ll * K + _ko, _la + 8192); \
    gload16(Asrc + 192ll * K + _ko, _la + 12288); \
    gload16(Bsrc + _ko,             _lb); \
    gload16(Bsrc + 64ll * K + _ko,  _lb + 4096); \
    gload16(Bsrc + 128ll * K + _ko, _lb + 8192); \
    gload16(Bsrc + 192ll * K + _ko, _lb + 12288); \
  } while (0)

  const int arow = (wid >> 2) * 128 + (lane & 15);   // + mf*16
  const int bcol = (wid & 3) * 64 + (lane & 15);     // + nf*16
  const int sl0 = ((lane >> 4) ^ (lane & 7)) * 8;        // kk=0 swizzled slot
  const int sl1 = ((4 + (lane >> 4)) ^ (lane & 7)) * 8;  // kk=1

  f32x4 acc[8][4];
#pragma unroll
  for (int m = 0; m < 8; ++m)
#pragma unroll
    for (int n = 0; n < 4; ++n) {
      f32x4 z = {0.f, 0.f, 0.f, 0.f};
      acc[m][n] = z;
    }

  STAGE(0, 0);
  const int NT = K >> 6;
  for (int t = 0; t < NT; ++t) {
    const int cb = (t & 1) * 32768;
    asm volatile("s_waitcnt vmcnt(0)" ::: "memory");  // tile t landed (8 loads, ~1 tile of flight)
    __builtin_amdgcn_s_barrier();
    __builtin_amdgcn_sched_barrier(0);
    if (t + 1 < NT) STAGE(t + 1, (t & 1) ^ 1);        // flies during this tile's compute
    const unsigned short* As = ls + cb;
    const unsigned short* Bs = ls + cb + 16384;
    bf16x8 af[8], bfr[4];
    // kk = 0
#pragma unroll
    for (int mf = 0; mf < 8; ++mf)
      af[mf] = *(const bf16x8*)&As[(arow + mf * 16) * 64 + sl0];
#pragma unroll
    for (int nf = 0; nf < 4; ++nf)
      bfr[nf] = *(const bf16x8*)&Bs[(bcol + nf * 16) * 64 + sl0];
    __builtin_amdgcn_s_setprio(1);
#pragma unroll
    for (int mf = 0; mf < 8; ++mf)
#pragma unroll
      for (int nf = 0; nf < 4; ++nf)
        acc[mf][nf] = __builtin_amdgcn_mfma_f32_16x16x32_bf16(af[mf], bfr[nf], acc[mf][nf], 0, 0, 0);
    __builtin_amdgcn_s_setprio(0);
    // kk = 1
#pragma unroll
    for (int mf = 0; mf < 8; ++mf)
      af[mf] = *(const bf16x8*)&As[(arow + mf * 16) * 64 + sl1];
#pragma unroll
    for (int nf = 0; nf < 4; ++nf)
      bfr[nf] = *(const bf16x8*)&Bs[(bcol + nf * 16) * 64 + sl1];
    __builtin_amdgcn_s_setprio(1);
#pragma unroll
    for (int mf = 0; mf < 8; ++mf)
#pragma unroll
      for (int nf = 0; nf < 4; ++nf)
        acc[mf][nf] = __builtin_amdgcn_mfma_f32_16x16x32_bf16(af[mf], bfr[nf], acc[mf][nf], 0, 0, 0);
    __builtin_amdgcn_s_setprio(0);
  }
#undef STAGE

  // ---------------- epilogues (round-7 verified geometry) ----------------
  if (EPI == 0 || EPI == 3) {
    unsigned short* C = (unsigned short*)Cp + (long long)bb * sC;
    const float* inv = (EPI == 3) ? (extra + (long long)bb * 2048) : nullptr;
#pragma unroll
    for (int mf = 0; mf < 8; ++mf)
#pragma unroll
      for (int nf = 0; nf < 4; ++nf)
#pragma unroll
        for (int i = 0; i < 4; ++i) {
          int gr = row0 + (wid >> 2) * 128 + mf * 16 + (lane >> 4) * 4 + i;
          int gc = col0 + (wid & 3) * 64 + nf * 16 + (lane & 15);
          float x = acc[mf][nf][i];
          if (EPI == 3) x *= inv[gr];
          C[(long long)gr * N + gc] = f2bf(x);
        }
  } else if (EPI == 2) {
    unsigned short* C = (unsigned short*)Cp;
#pragma unroll
    for (int mf = 0; mf < 8; ++mf)
#pragma unroll
      for (int nf = 0; nf < 4; ++nf) {
        int gr = row0 + (wid >> 2) * 128 + mf * 16 + (lane >> 4) * 4;
        int gc = col0 + (wid & 3) * 64 + nf * 16 + (lane & 15);
        int bb2 = gr >> 11, grb = gr & 2047;
        us4 o;
        o[0] = f2bf(acc[mf][nf][0]); o[1] = f2bf(acc[mf][nf][1]);
        o[2] = f2bf(acc[mf][nf][2]); o[3] = f2bf(acc[mf][nf][3]);
        *(us4*)&C[(long long)bb2 * sC + (long long)gc * 2048 + grb] = o;
      }
  } else {   // EPI 1: scores
    unsigned short* C = (unsigned short*)Cp + (long long)bb * sC;
    float rs[8][4];
#pragma unroll
    for (int mf = 0; mf < 8; ++mf)
#pragma unroll
      for (int i = 0; i < 4; ++i) rs[mf][i] = 0.f;
#pragma unroll
    for (int mf = 0; mf < 8; ++mf)
#pragma unroll
      for (int nf = 0; nf < 4; ++nf)
#pragma unroll
        for (int i = 0; i < 4; ++i) {
          int gr = row0 + (wid >> 2) * 128 + mf * 16 + (lane >> 4) * 4 + i;
          int gc = col0 + (wid & 3) * 64 + nf * 16 + (lane & 15);
          float s = acc[mf][nf][i] * 0.03125f;   // 1/sqrt(1024)
          s = (s < 0.9f) ? 0.f : s;              // threshold BEFORE softmax
          float e = __expf(s);                   // bounded: no max-subtraction
          C[(long long)gr * N + gc] = f2bf(e);
          rs[mf][i] += e;
        }
#pragma unroll
    for (int mf = 0; mf < 8; ++mf)
#pragma unroll
      for (int i = 0; i < 4; ++i) {
        float vv = rs[mf][i];
        vv += __shfl_xor(vv, 1); vv += __shfl_xor(vv, 2);
        vv += __shfl_xor(vv, 4); vv += __shfl_xor(vv, 8);
        if ((lane & 15) == 0)
          srow[(wid >> 2) * 128 + mf * 16 + (lane >> 4) * 4 + i][wid & 3] = vv;
      }
    __syncthreads();
    if (tid < 256) {
      int gr = row0 + tid;
      extra[((long long)bb * M + gr) * nbn + bn] =
          srow[tid][0] + srow[tid][1] + srow[tid][2] + srow[tid][3];
    }
  }
}

// ---------------------------------------------------------------------------
// q,k,v fp32 -> bf16, one pass (8 elem/thread each)
// ---------------------------------------------------------------------------
__global__ __launch_bounds__(256)
void cvt3(const float* __restrict__ a, const float* __restrict__ b,
          const float* __restrict__ c, unsigned short* __restrict__ oa,
          unsigned short* __restrict__ ob, unsigned short* __restrict__ oc) {
  const long long i = ((long long)blockIdx.x * 256 + threadIdx.x) * 8;
#pragma unroll
  for (int p = 0; p < 3; ++p) {
    const float* src = (p == 0) ? a : (p == 1) ? b : c;
    unsigned short* dst = (p == 0) ? oa : (p == 1) ? ob : oc;
    f32x4 x0 = *(const f32x4*)(src + i);
    f32x4 x1 = *(const f32x4*)(src + i + 4);
    us8 o;
    o[0] = f2bf(x0[0]); o[1] = f2bf(x0[1]); o[2] = f2bf(x0[2]); o[3] = f2bf(x0[3]);
    o[4] = f2bf(x1[0]); o[5] = f2bf(x1[1]); o[6] = f2bf(x1[2]); o[7] = f2bf(x1[3]);
    *(us8*)(dst + i) = o;
  }
}

// ---------------------------------------------------------------------------
// 4 weight transposes in one launch: W[1024][1024] f32 -> WT bf16 transposed
// ---------------------------------------------------------------------------
__global__ __launch_bounds__(256)
void wtrans4(const float* __restrict__ W0, const float* __restrict__ W1,
             const float* __restrict__ W2, const float* __restrict__ W3,
             unsigned short* __restrict__ T0, unsigned short* __restrict__ T1,
             unsigned short* __restrict__ T2, unsigned short* __restrict__ T3) {
  __shared__ float t[32][33];
  const int z = blockIdx.z;
  const float* W = (z == 0) ? W0 : (z == 1) ? W1 : (z == 2) ? W2 : W3;
  unsigned short* WT = (z == 0) ? T0 : (z == 1) ? T1 : (z == 2) ? T2 : T3;
  const int bi = blockIdx.x, bj = blockIdx.y;
  const int c = threadIdx.x & 31;
  const int r0 = threadIdx.x >> 5;
#pragma unroll
  for (int j = 0; j < 4; ++j) {
    int r = r0 + j * 8;
    t[r][c] = W[(long long)(bi * 32 + r) * 1024 + bj * 32 + c];
  }
  __syncthreads();
#pragma unroll
  for (int j = 0; j < 4; ++j) {
    int r = r0 + j * 8;
    WT[(long long)(bj * 32 + r) * 1024 + bi * 32 + c] = f2bf(t[c][r]);
  }
}

// ---------------------------------------------------------------------------
// attn f32 output + inv_dens from bf16 exp-scores and partials (width 8)
// ---------------------------------------------------------------------------
__global__ __launch_bounds__(256)
void attn_norm(const unsigned short* __restrict__ e, const float* __restrict__ partials,
               float* __restrict__ attn, float* __restrict__ inv_dens) {
  const long long row = blockIdx.x;
  const int tid = threadIdx.x;
  __shared__ float sden;
  if (tid < 64) {
    float v = (tid < 8) ? partials[row * 8 + tid] : 0.f;
    v += __shfl_xor(v, 1); v += __shfl_xor(v, 2); v += __shfl_xor(v, 4);
    if (tid == 0) sden = v;
  }
  __syncthreads();
  const float inv = 1.0f / sden;
  if (tid == 0) inv_dens[row] = inv;
  us8 x = *(const us8*)(e + row * 2048 + tid * 8);
  f32x4 y0, y1;
#pragma unroll
  for (int i = 0; i < 4; ++i) { y0[i] = bf2f(x[i]) * inv; y1[i] = bf2f(x[i + 4]) * inv; }
  *(f32x4*)(attn + row * 2048 + tid * 8) = y0;
  *(f32x4*)(attn + row * 2048 + tid * 8 + 4) = y1;
}

// ---------------------------------------------------------------------------
// out(f32) = LayerNorm(fc(bf16) + qres) * gamma + beta   (row = 1024)
// QB16: residual read as bf16 (32MB) instead of f32 q (64MB)
// ---------------------------------------------------------------------------
template <bool QB16>
__global__ __launch_bounds__(256)
void ln_kernel(const unsigned short* __restrict__ fc, const void* __restrict__ qres,
               const float* __restrict__ gamma, const float* __restrict__ beta,
               float* __restrict__ out) {
  const long long row = blockIdx.x;
  const int tid = threadIdx.x;
  __shared__ float sb1[4], sb2[4];
  us4 hv = *(const us4*)(fc + row * 1024 + tid * 4);
  float q0, q1, q2, q3;
  if (QB16) {
    us4 qv = *(const us4*)((const unsigned short*)qres + row * 1024 + tid * 4);
    q0 = bf2f(qv[0]); q1 = bf2f(qv[1]); q2 = bf2f(qv[2]); q3 = bf2f(qv[3]);
  } else {
    f32x4 qv = *(const f32x4*)((const float*)qres + row * 1024 + tid * 4);
    q0 = qv[0]; q1 = qv[1]; q2 = qv[2]; q3 = qv[3];
  }
  float x0 = bf2f(hv[0]) + q0;
  float x1 = bf2f(hv[1]) + q1;
  float x2 = bf2f(hv[2]) + q2;
  float x3 = bf2f(hv[3]) + q3;
  float s = x0 + x1 + x2 + x3;
#pragma unroll
  for (int m = 1; m < 64; m <<= 1) s += __shfl_xor(s, m);
  if ((tid & 63) == 0) sb1[tid >> 6] = s;
  __syncthreads();
  const float mean = (sb1[0] + sb1[1] + sb1[2] + sb1[3]) * (1.0f / 1024.0f);
  float d0 = x0 - mean, d1 = x1 - mean, d2 = x2 - mean, d3 = x3 - mean;
  float vs = d0 * d0 + d1 * d1 + d2 * d2 + d3 * d3;
#pragma unroll
  for (int m = 1; m < 64; m <<= 1) vs += __shfl_xor(vs, m);
  if ((tid & 63) == 0) sb2[tid >> 6] = vs;
  __syncthreads();
  const float var = (sb2[0] + sb2[1] + sb2[2] + sb2[3]) * (1.0f / 1024.0f);
  const float r = rsqrtf(var + 1e-6f);
  f32x4 g = *(const f32x4*)(gamma + tid * 4);
  f32x4 bt = *(const f32x4*)(beta + tid * 4);
  f32x4 o;
  o[0] = d0 * r * g[0] + bt[0];
  o[1] = d1 * r * g[1] + bt[1];
  o[2] = d2 * r * g[2] + bt[2];
  o[3] = d3 * r * g[3] + bt[3];
  *(f32x4*)(out + row * 1024 + tid * 4) = o;
}

// ---------------------------------------------------------------------------
// d_out = [ out0 f32 64MB | attn f32 128MB ].  Scratch timeline:
//   attn region: kb@+32M, vb@+64M (cvt) -> qh@+96M -> kh@+0 -> attn f32 (norm)
//   out0 region: vhT@+0, out_mid@+32M; ln overwrites last.
// ws: W*T @0/2/4/6M; partials@8M ([16384][8]); inv_dens@10M; e bf16 @11M
//   (64MB); fc reuses e after PV; qb @76M if ws_size >= 110MB (else attn rgn).
// ---------------------------------------------------------------------------
extern "C" void kernel_launch(void* const* d_in, const int* in_sizes, int n_in,
                              void* d_out, int out_size, void* d_ws, size_t ws_size,
                              hipStream_t stream) {
  const float* q    = (const float*)d_in[0];
  const float* k    = (const float*)d_in[1];
  const float* v    = (const float*)d_in[2];
  const float* Wq   = (const float*)d_in[3];
  const float* Wk   = (const float*)d_in[4];
  const float* Wv   = (const float*)d_in[5];
  const float* Wfc  = (const float*)d_in[6];
  const float* gamma = (const float*)d_in[7];
  const float* beta  = (const float*)d_in[8];

  float* out0 = (float*)d_out;
  float* attn = out0 + (long long)8 * 2048 * 1024;

  char* ao = (char*)attn;
  unsigned short* kb = (unsigned short*)(ao + (32ll << 20));
  unsigned short* vb = (unsigned short*)(ao + (64ll << 20));
  unsigned short* qh = (unsigned short*)(ao + (96ll << 20));
  unsigned short* kh = (unsigned short*)(ao);
  unsigned short* vhT     = (unsigned short*)d_out;
  unsigned short* out_mid = (unsigned short*)((char*)d_out + (32ll << 20));

  char* ws = (char*)d_ws;
  unsigned short* WqT  = (unsigned short*)(ws);
  unsigned short* WkT  = (unsigned short*)(ws + (2ll  << 20));
  unsigned short* WvT  = (unsigned short*)(ws + (4ll  << 20));
  unsigned short* WfcT = (unsigned short*)(ws + (6ll  << 20));
  float* partials      = (float*)(ws + (8ll  << 20));            // [16384][8]
  float* inv_dens      = (float*)(ws + (10ll << 20));            // [16384]
  unsigned short* e    = (unsigned short*)(ws + (11ll << 20));   // 64MB
  unsigned short* fc   = e;
  const bool qb_ws = ws_size >= (110ll << 20);
  unsigned short* qb = qb_ws ? (unsigned short*)(ws + (76ll << 20))
                             : (unsigned short*)(ao);             // fallback: qb dies at kh

  // 1. conversions
  cvt3<<<dim3(8192), 256, 0, stream>>>(q, k, v, qb, kb, vb);
  wtrans4<<<dim3(32, 32, 4), 256, 0, stream>>>(Wq, Wk, Wv, Wfc, WqT, WkT, WvT, WfcT);

  // 2. projections (M=16384 batch-folded; 256² tiles: nbm=64, nbn=4)
  gemm2p<0><<<dim3(256, 1), 512, 0, stream>>>(qb, WqT, qh, nullptr,
      16384, 1024, 1024, 64, 4, 0, 0, 0);
  gemm2p<0><<<dim3(256, 1), 512, 0, stream>>>(kb, WkT, kh, nullptr,
      16384, 1024, 1024, 64, 4, 0, 0, 0);
  gemm2p<2><<<dim3(256, 1), 512, 0, stream>>>(vb, WvT, vhT, nullptr,
      16384, 1024, 1024, 64, 4, 0, 0, 1024ll * 2048);   // vhT[b][d][s]

  // 3. scores: e = exp(thresh(qh kh^T / 32)) bf16 + partial row sums (w=8)
  gemm2p<1><<<dim3(64, 8), 512, 0, stream>>>(qh, kh, e, partials,
      2048, 2048, 1024, 8, 8, 2048ll * 1024, 2048ll * 1024, 2048ll * 2048);

  // 4. attn(f32) = e/den; inv_dens
  attn_norm<<<dim3(16384), 256, 0, stream>>>(e, partials, attn, inv_dens);

  // 5. PV: out_mid = (e @ vh) * inv_den[row]   (nbm=8, nbn=4)
  gemm2p<3><<<dim3(32, 8), 512, 0, stream>>>(e, vhT, out_mid, inv_dens,
      2048, 1024, 2048, 8, 4, 2048ll * 2048, 1024ll * 2048, 2048ll * 1024);

  // 6. FC: fc = out_mid @ Wfc
  gemm2p<0><<<dim3(256, 1), 512, 0, stream>>>(out_mid, WfcT, fc, nullptr,
      16384, 1024, 1024, 64, 4, 0, 0, 0);

  // 7. out0 = LN(fc + q)
  if (qb_ws)
    ln_kernel<true><<<dim3(16384), 256, 0, stream>>>(fc, qb, gamma, beta, out0);
  else
    ln_kernel<false><<<dim3(16384), 256, 0, stream>>>(fc, q, gamma, beta, out0);
}

// Round 10
// 404.443 us; speedup vs baseline: 1.1033x; 1.0178x over previous
//
#include <hip/hip_runtime.h>
#include <hip/hip_bf16.h>
#include <stdint.h>

typedef __attribute__((ext_vector_type(8))) short bf16x8;
typedef __attribute__((ext_vector_type(4))) float f32x4;
typedef __attribute__((ext_vector_type(4))) unsigned short us4;
typedef __attribute__((ext_vector_type(8))) unsigned short us8;

__device__ __forceinline__ unsigned short f2bf(float f) {
  union { float f; unsigned int u; } v; v.f = f;
  unsigned int u = v.u;
  return (unsigned short)((u + 0x7FFFu + ((u >> 16) & 1u)) >> 16);
}
__device__ __forceinline__ float bf2f(unsigned short h) {
  union { unsigned int u; float f; } v; v.u = ((unsigned int)h) << 16;
  return v.f;
}

// async global->LDS, 16B per lane; LDS dest = wave-uniform base + lane*16
__device__ __forceinline__ void gload16(const unsigned short* g, unsigned short* l) {
  __builtin_amdgcn_global_load_lds(
      (const __attribute__((address_space(1))) unsigned int*)g,
      (__attribute__((address_space(3))) unsigned int*)l, 16, 0, 0);
}

// ---------------------------------------------------------------------------
// 128x128 NT GEMM (r8-verified, m97-class). Used for SCORES: its 2048-block
// grid gets multi-block/CU overlap that beats the 1-block/CU 256² kernel.
// EPI 1 only here: s=acc/32; thr 0.9; e=exp(s); bf16 e + width-16 partials.
// ---------------------------------------------------------------------------
template <int EPI>
__global__ __launch_bounds__(256, 2)
void gemm_nt(const unsigned short* __restrict__ Ap, const unsigned short* __restrict__ Btp,
             void* __restrict__ Cp, float* __restrict__ extra,
             int M, int N, int K, int nbm,
             long long sA, long long sB, long long sC)
{
  const int tid = threadIdx.x;
  const int lane = tid & 63;
  const int wid = tid >> 6;
  const int wr = wid >> 1, wc = wid & 1;
  const int bb = blockIdx.y;
  const int bm = blockIdx.x % nbm, bn = blockIdx.x / nbm;
  const int row0 = bm * 128, col0 = bn * 128;

  __shared__ unsigned short lsA[128 * 64];   // [row][8 slots of 16B], swizzled
  __shared__ unsigned short lsB[128 * 64];
  __shared__ float srow2[128][2];

  const unsigned short* Ab = Ap + (long long)bb * sA;
  const unsigned short* Bb = Btp + (long long)bb * sB;

  const int srow = wid * 32 + (lane >> 3);
  const int sslot = (lane & 7) ^ (lane >> 3);
  const unsigned short* Asrc = Ab + (long long)(row0 + srow) * K + sslot * 8;
  const unsigned short* Bsrc = Bb + (long long)(col0 + srow) * K + sslot * 8;
  unsigned short* ldsA0 = &lsA[wid * 2048];
  unsigned short* ldsB0 = &lsB[wid * 2048];

  f32x4 acc[4][4];
#pragma unroll
  for (int i = 0; i < 4; ++i)
#pragma unroll
    for (int j = 0; j < 4; ++j) {
      f32x4 z = {0.f, 0.f, 0.f, 0.f};
      acc[i][j] = z;
    }

  for (int k0 = 0; k0 < K; k0 += 64) {
    __syncthreads();
#pragma unroll
    for (int it = 0; it < 4; ++it) {
      gload16(Asrc + (long long)it * 8 * K + k0, ldsA0 + it * 512);
      gload16(Bsrc + (long long)it * 8 * K + k0, ldsB0 + it * 512);
    }
    __syncthreads();
#pragma unroll
    for (int kk = 0; kk < 2; ++kk) {
      int kslot = kk * 4 + (lane >> 4);
      bf16x8 af[4], bfg[4];
#pragma unroll
      for (int mf = 0; mf < 4; ++mf) {
        int rl = wr * 64 + mf * 16 + (lane & 15);
        af[mf] = *(const bf16x8*)&lsA[rl * 64 + ((kslot ^ (rl & 7)) * 8)];
      }
#pragma unroll
      for (int nf = 0; nf < 4; ++nf) {
        int cl = wc * 64 + nf * 16 + (lane & 15);
        bfg[nf] = *(const bf16x8*)&lsB[cl * 64 + ((kslot ^ (cl & 7)) * 8)];
      }
#pragma unroll
      for (int mf = 0; mf < 4; ++mf)
#pragma unroll
        for (int nf = 0; nf < 4; ++nf)
          acc[mf][nf] = __builtin_amdgcn_mfma_f32_16x16x32_bf16(af[mf], bfg[nf], acc[mf][nf], 0, 0, 0);
    }
  }

  unsigned short* C = (unsigned short*)Cp + (long long)bb * sC;
  if (EPI == 0) {
#pragma unroll
    for (int mf = 0; mf < 4; ++mf)
#pragma unroll
      for (int nf = 0; nf < 4; ++nf)
#pragma unroll
        for (int i = 0; i < 4; ++i) {
          int gr = row0 + wr * 64 + mf * 16 + (lane >> 4) * 4 + i;
          int gc = col0 + wc * 64 + nf * 16 + (lane & 15);
          C[(long long)gr * N + gc] = f2bf(acc[mf][nf][i]);
        }
  } else {   // EPI 1: scores
    float rs[4][4];
#pragma unroll
    for (int mf = 0; mf < 4; ++mf)
#pragma unroll
      for (int i = 0; i < 4; ++i) rs[mf][i] = 0.f;
#pragma unroll
    for (int mf = 0; mf < 4; ++mf)
#pragma unroll
      for (int nf = 0; nf < 4; ++nf)
#pragma unroll
        for (int i = 0; i < 4; ++i) {
          int gr = row0 + wr * 64 + mf * 16 + (lane >> 4) * 4 + i;
          int gc = col0 + wc * 64 + nf * 16 + (lane & 15);
          float s = acc[mf][nf][i] * 0.03125f;   // 1/sqrt(1024)
          s = (s < 0.9f) ? 0.f : s;              // hard threshold BEFORE softmax
          float e = __expf(s);                   // bounded by ~e^6: no max-sub
          C[(long long)gr * N + gc] = f2bf(e);
          rs[mf][i] += e;
        }
#pragma unroll
    for (int mf = 0; mf < 4; ++mf)
#pragma unroll
      for (int i = 0; i < 4; ++i) {
        float vv = rs[mf][i];
        vv += __shfl_xor(vv, 1); vv += __shfl_xor(vv, 2);
        vv += __shfl_xor(vv, 4); vv += __shfl_xor(vv, 8);
        if ((lane & 15) == 0)
          srow2[wr * 64 + mf * 16 + (lane >> 4) * 4 + i][wc] = vv;
      }
    __syncthreads();
    if (tid < 128) {
      int gr = row0 + tid;
      extra[((long long)bb * M + gr) * 16 + bn] = srow2[tid][0] + srow2[tid][1];
    }
  }
}

// ---------------------------------------------------------------------------
// 256x256 NT GEMM, 2-phase counted pipeline (r9-verified). Used for
// projections / PV / FC (small grids where pipeline flight beats block TLP).
// EPI 0: bf16 C row-major; EPI 2: bf16 C transposed per batch (v-proj);
// EPI 3: bf16 acc*inv[row] (PV).
// ---------------------------------------------------------------------------
template <int EPI>
__global__ __launch_bounds__(512, 2)
void gemm2p(const unsigned short* __restrict__ Ap, const unsigned short* __restrict__ Btp,
            void* __restrict__ Cp, float* __restrict__ extra,
            int M, int N, int K, int nbm, int nbn,
            long long sA, long long sB, long long sC)
{
  __shared__ unsigned short ls[65536];   // 128 KiB: [buf 32768][A 16384 | B 16384]

  const int tid = threadIdx.x;
  const int lane = tid & 63;
  const int wid = tid >> 6;
  const int bb = blockIdx.y;
  const int bm = blockIdx.x % nbm, bn = blockIdx.x / nbm;
  const int row0 = bm * 256, col0 = bn * 256;

  const unsigned short* Ab = Ap + (long long)bb * sA;
  const unsigned short* Bb = Btp + (long long)bb * sB;

  const int srw = tid >> 3;
  const int ssl = (tid & 7) ^ ((tid >> 3) & 7);
  const unsigned short* Asrc = Ab + (long long)(row0 + srw) * K + ssl * 8;
  const unsigned short* Bsrc = Bb + (long long)(col0 + srw) * K + ssl * 8;

#define STAGE(KT, BUF) do { \
    unsigned short* _la = ls + (BUF) * 32768 + wid * 512; \
    unsigned short* _lb = _la + 16384; \
    const long long _ko = (long long)(KT) * 64; \
    gload16(Asrc + _ko,             _la); \
    gload16(Asrc + 64ll * K + _ko,  _la + 4096); \
    gload16(Asrc + 128ll * K + _ko, _la + 8192); \
    gload16(Asrc + 192ll * K + _ko, _la + 12288); \
    gload16(Bsrc + _ko,             _lb); \
    gload16(Bsrc + 64ll * K + _ko,  _lb + 4096); \
    gload16(Bsrc + 128ll * K + _ko, _lb + 8192); \
    gload16(Bsrc + 192ll * K + _ko, _lb + 12288); \
  } while (0)

  const int arow = (wid >> 2) * 128 + (lane & 15);
  const int bcol = (wid & 3) * 64 + (lane & 15);
  const int sl0 = ((lane >> 4) ^ (lane & 7)) * 8;
  const int sl1 = ((4 + (lane >> 4)) ^ (lane & 7)) * 8;

  f32x4 acc[8][4];
#pragma unroll
  for (int m = 0; m < 8; ++m)
#pragma unroll
    for (int n = 0; n < 4; ++n) {
      f32x4 z = {0.f, 0.f, 0.f, 0.f};
      acc[m][n] = z;
    }

  STAGE(0, 0);
  const int NT = K >> 6;
  for (int t = 0; t < NT; ++t) {
    const int cb = (t & 1) * 32768;
    asm volatile("s_waitcnt vmcnt(0)" ::: "memory");
    __builtin_amdgcn_s_barrier();
    __builtin_amdgcn_sched_barrier(0);
    if (t + 1 < NT) STAGE(t + 1, (t & 1) ^ 1);
    const unsigned short* As = ls + cb;
    const unsigned short* Bs = ls + cb + 16384;
    bf16x8 af[8], bfr[4];
#pragma unroll
    for (int mf = 0; mf < 8; ++mf)
      af[mf] = *(const bf16x8*)&As[(arow + mf * 16) * 64 + sl0];
#pragma unroll
    for (int nf = 0; nf < 4; ++nf)
      bfr[nf] = *(const bf16x8*)&Bs[(bcol + nf * 16) * 64 + sl0];
    __builtin_amdgcn_s_setprio(1);
#pragma unroll
    for (int mf = 0; mf < 8; ++mf)
#pragma unroll
      for (int nf = 0; nf < 4; ++nf)
        acc[mf][nf] = __builtin_amdgcn_mfma_f32_16x16x32_bf16(af[mf], bfr[nf], acc[mf][nf], 0, 0, 0);
    __builtin_amdgcn_s_setprio(0);
#pragma unroll
    for (int mf = 0; mf < 8; ++mf)
      af[mf] = *(const bf16x8*)&As[(arow + mf * 16) * 64 + sl1];
#pragma unroll
    for (int nf = 0; nf < 4; ++nf)
      bfr[nf] = *(const bf16x8*)&Bs[(bcol + nf * 16) * 64 + sl1];
    __builtin_amdgcn_s_setprio(1);
#pragma unroll
    for (int mf = 0; mf < 8; ++mf)
#pragma unroll
      for (int nf = 0; nf < 4; ++nf)
        acc[mf][nf] = __builtin_amdgcn_mfma_f32_16x16x32_bf16(af[mf], bfr[nf], acc[mf][nf], 0, 0, 0);
    __builtin_amdgcn_s_setprio(0);
  }
#undef STAGE

  if (EPI == 0 || EPI == 3) {
    unsigned short* C = (unsigned short*)Cp + (long long)bb * sC;
    const float* inv = (EPI == 3) ? (extra + (long long)bb * 2048) : nullptr;
#pragma unroll
    for (int mf = 0; mf < 8; ++mf)
#pragma unroll
      for (int nf = 0; nf < 4; ++nf)
#pragma unroll
        for (int i = 0; i < 4; ++i) {
          int gr = row0 + (wid >> 2) * 128 + mf * 16 + (lane >> 4) * 4 + i;
          int gc = col0 + (wid & 3) * 64 + nf * 16 + (lane & 15);
          float x = acc[mf][nf][i];
          if (EPI == 3) x *= inv[gr];
          C[(long long)gr * N + gc] = f2bf(x);
        }
  } else if (EPI == 2) {
    unsigned short* C = (unsigned short*)Cp;
#pragma unroll
    for (int mf = 0; mf < 8; ++mf)
#pragma unroll
      for (int nf = 0; nf < 4; ++nf) {
        int gr = row0 + (wid >> 2) * 128 + mf * 16 + (lane >> 4) * 4;
        int gc = col0 + (wid & 3) * 64 + nf * 16 + (lane & 15);
        int bb2 = gr >> 11, grb = gr & 2047;
        us4 o;
        o[0] = f2bf(acc[mf][nf][0]); o[1] = f2bf(acc[mf][nf][1]);
        o[2] = f2bf(acc[mf][nf][2]); o[3] = f2bf(acc[mf][nf][3]);
        *(us4*)&C[(long long)bb2 * sC + (long long)gc * 2048 + grb] = o;
      }
  }
}

// ---------------------------------------------------------------------------
// q,k,v fp32 -> bf16, one pass (8 elem/thread each)
// ---------------------------------------------------------------------------
__global__ __launch_bounds__(256)
void cvt3(const float* __restrict__ a, const float* __restrict__ b,
          const float* __restrict__ c, unsigned short* __restrict__ oa,
          unsigned short* __restrict__ ob, unsigned short* __restrict__ oc) {
  const long long i = ((long long)blockIdx.x * 256 + threadIdx.x) * 8;
#pragma unroll
  for (int p = 0; p < 3; ++p) {
    const float* src = (p == 0) ? a : (p == 1) ? b : c;
    unsigned short* dst = (p == 0) ? oa : (p == 1) ? ob : oc;
    f32x4 x0 = *(const f32x4*)(src + i);
    f32x4 x1 = *(const f32x4*)(src + i + 4);
    us8 o;
    o[0] = f2bf(x0[0]); o[1] = f2bf(x0[1]); o[2] = f2bf(x0[2]); o[3] = f2bf(x0[3]);
    o[4] = f2bf(x1[0]); o[5] = f2bf(x1[1]); o[6] = f2bf(x1[2]); o[7] = f2bf(x1[3]);
    *(us8*)(dst + i) = o;
  }
}

// ---------------------------------------------------------------------------
// 4 weight transposes in one launch: W[1024][1024] f32 -> WT bf16 transposed
// ---------------------------------------------------------------------------
__global__ __launch_bounds__(256)
void wtrans4(const float* __restrict__ W0, const float* __restrict__ W1,
             const float* __restrict__ W2, const float* __restrict__ W3,
             unsigned short* __restrict__ T0, unsigned short* __restrict__ T1,
             unsigned short* __restrict__ T2, unsigned short* __restrict__ T3) {
  __shared__ float t[32][33];
  const int z = blockIdx.z;
  const float* W = (z == 0) ? W0 : (z == 1) ? W1 : (z == 2) ? W2 : W3;
  unsigned short* WT = (z == 0) ? T0 : (z == 1) ? T1 : (z == 2) ? T2 : T3;
  const int bi = blockIdx.x, bj = blockIdx.y;
  const int c = threadIdx.x & 31;
  const int r0 = threadIdx.x >> 5;
#pragma unroll
  for (int j = 0; j < 4; ++j) {
    int r = r0 + j * 8;
    t[r][c] = W[(long long)(bi * 32 + r) * 1024 + bj * 32 + c];
  }
  __syncthreads();
#pragma unroll
  for (int j = 0; j < 4; ++j) {
    int r = r0 + j * 8;
    WT[(long long)(bj * 32 + r) * 1024 + bi * 32 + c] = f2bf(t[c][r]);
  }
}

// ---------------------------------------------------------------------------
// attn f32 output + inv_dens from bf16 exp-scores and partials (width 16)
// ---------------------------------------------------------------------------
__global__ __launch_bounds__(256)
void attn_norm(const unsigned short* __restrict__ e, const float* __restrict__ partials,
               float* __restrict__ attn, float* __restrict__ inv_dens) {
  const long long row = blockIdx.x;
  const int tid = threadIdx.x;
  __shared__ float sden;
  if (tid < 64) {
    float v = (tid < 16) ? partials[row * 16 + tid] : 0.f;
    v += __shfl_xor(v, 1); v += __shfl_xor(v, 2);
    v += __shfl_xor(v, 4); v += __shfl_xor(v, 8);
    if (tid == 0) sden = v;
  }
  __syncthreads();
  const float inv = 1.0f / sden;
  if (tid == 0) inv_dens[row] = inv;
  us8 x = *(const us8*)(e + row * 2048 + tid * 8);
  f32x4 y0, y1;
#pragma unroll
  for (int i = 0; i < 4; ++i) { y0[i] = bf2f(x[i]) * inv; y1[i] = bf2f(x[i + 4]) * inv; }
  *(f32x4*)(attn + row * 2048 + tid * 8) = y0;
  *(f32x4*)(attn + row * 2048 + tid * 8 + 4) = y1;
}

// ---------------------------------------------------------------------------
// out(f32) = LayerNorm(fc(bf16) + qres) * gamma + beta   (row = 1024)
// QB16: residual read as bf16 (32MB) instead of f32 q (64MB)
// ---------------------------------------------------------------------------
template <bool QB16>
__global__ __launch_bounds__(256)
void ln_kernel(const unsigned short* __restrict__ fc, const void* __restrict__ qres,
               const float* __restrict__ gamma, const float* __restrict__ beta,
               float* __restrict__ out) {
  const long long row = blockIdx.x;
  const int tid = threadIdx.x;
  __shared__ float sb1[4], sb2[4];
  us4 hv = *(const us4*)(fc + row * 1024 + tid * 4);
  float q0, q1, q2, q3;
  if (QB16) {
    us4 qv = *(const us4*)((const unsigned short*)qres + row * 1024 + tid * 4);
    q0 = bf2f(qv[0]); q1 = bf2f(qv[1]); q2 = bf2f(qv[2]); q3 = bf2f(qv[3]);
  } else {
    f32x4 qv = *(const f32x4*)((const float*)qres + row * 1024 + tid * 4);
    q0 = qv[0]; q1 = qv[1]; q2 = qv[2]; q3 = qv[3];
  }
  float x0 = bf2f(hv[0]) + q0;
  float x1 = bf2f(hv[1]) + q1;
  float x2 = bf2f(hv[2]) + q2;
  float x3 = bf2f(hv[3]) + q3;
  float s = x0 + x1 + x2 + x3;
#pragma unroll
  for (int m = 1; m < 64; m <<= 1) s += __shfl_xor(s, m);
  if ((tid & 63) == 0) sb1[tid >> 6] = s;
  __syncthreads();
  const float mean = (sb1[0] + sb1[1] + sb1[2] + sb1[3]) * (1.0f / 1024.0f);
  float d0 = x0 - mean, d1 = x1 - mean, d2 = x2 - mean, d3 = x3 - mean;
  float vs = d0 * d0 + d1 * d1 + d2 * d2 + d3 * d3;
#pragma unroll
  for (int m = 1; m < 64; m <<= 1) vs += __shfl_xor(vs, m);
  if ((tid & 63) == 0) sb2[tid >> 6] = vs;
  __syncthreads();
  const float var = (sb2[0] + sb2[1] + sb2[2] + sb2[3]) * (1.0f / 1024.0f);
  const float r = rsqrtf(var + 1e-6f);
  f32x4 g = *(const f32x4*)(gamma + tid * 4);
  f32x4 bt = *(const f32x4*)(beta + tid * 4);
  f32x4 o;
  o[0] = d0 * r * g[0] + bt[0];
  o[1] = d1 * r * g[1] + bt[1];
  o[2] = d2 * r * g[2] + bt[2];
  o[3] = d3 * r * g[3] + bt[3];
  *(f32x4*)(out + row * 1024 + tid * 4) = o;
}

// ---------------------------------------------------------------------------
// d_out = [ out0 f32 64MB | attn f32 128MB ].  Scratch timeline:
//   attn region: kb@+32M, vb@+64M (cvt) -> qh@+96M -> kh@+0 -> attn f32 (norm)
//   out0 region: vhT@+0, out_mid@+32M; ln overwrites last.
// ws: W*T @0/2/4/6M; partials@8M ([16384][16]); inv_dens@10M; e bf16 @11M
//   (64MB); fc reuses e after PV; qb @76M if ws_size >= 110MB (else attn rgn).
// ---------------------------------------------------------------------------
extern "C" void kernel_launch(void* const* d_in, const int* in_sizes, int n_in,
                              void* d_out, int out_size, void* d_ws, size_t ws_size,
                              hipStream_t stream) {
  const float* q    = (const float*)d_in[0];
  const float* k    = (const float*)d_in[1];
  const float* v    = (const float*)d_in[2];
  const float* Wq   = (const float*)d_in[3];
  const float* Wk   = (const float*)d_in[4];
  const float* Wv   = (const float*)d_in[5];
  const float* Wfc  = (const float*)d_in[6];
  const float* gamma = (const float*)d_in[7];
  const float* beta  = (const float*)d_in[8];

  float* out0 = (float*)d_out;
  float* attn = out0 + (long long)8 * 2048 * 1024;

  char* ao = (char*)attn;
  unsigned short* kb = (unsigned short*)(ao + (32ll << 20));
  unsigned short* vb = (unsigned short*)(ao + (64ll << 20));
  unsigned short* qh = (unsigned short*)(ao + (96ll << 20));
  unsigned short* kh = (unsigned short*)(ao);
  unsigned short* vhT     = (unsigned short*)d_out;
  unsigned short* out_mid = (unsigned short*)((char*)d_out + (32ll << 20));

  char* ws = (char*)d_ws;
  unsigned short* WqT  = (unsigned short*)(ws);
  unsigned short* WkT  = (unsigned short*)(ws + (2ll  << 20));
  unsigned short* WvT  = (unsigned short*)(ws + (4ll  << 20));
  unsigned short* WfcT = (unsigned short*)(ws + (6ll  << 20));
  float* partials      = (float*)(ws + (8ll  << 20));            // [16384][16]
  float* inv_dens      = (float*)(ws + (10ll << 20));            // [16384]
  unsigned short* e    = (unsigned short*)(ws + (11ll << 20));   // 64MB
  unsigned short* fc   = e;
  const bool qb_ws = ws_size >= (110ll << 20);
  unsigned short* qb = qb_ws ? (unsigned short*)(ws + (76ll << 20))
                             : (unsigned short*)(ao);             // fallback: qb dies at kh

  // 1. conversions
  cvt3<<<dim3(8192), 256, 0, stream>>>(q, k, v, qb, kb, vb);
  wtrans4<<<dim3(32, 32, 4), 256, 0, stream>>>(Wq, Wk, Wv, Wfc, WqT, WkT, WvT, WfcT);

  // 2. projections: 256² 2-phase (small grids -> pipeline flight wins)
  gemm2p<0><<<dim3(256, 1), 512, 0, stream>>>(qb, WqT, qh, nullptr,
      16384, 1024, 1024, 64, 4, 0, 0, 0);
  gemm2p<0><<<dim3(256, 1), 512, 0, stream>>>(kb, WkT, kh, nullptr,
      16384, 1024, 1024, 64, 4, 0, 0, 0);
  gemm2p<2><<<dim3(256, 1), 512, 0, stream>>>(vb, WvT, vhT, nullptr,
      16384, 1024, 1024, 64, 4, 0, 0, 1024ll * 2048);   // vhT[b][d][s]

  // 3. scores: 128² (2048-block grid -> block-level TLP wins), width-16 partials
  gemm_nt<1><<<dim3(256, 8), 256, 0, stream>>>(qh, kh, e, partials,
      2048, 2048, 1024, 16, 2048ll * 1024, 2048ll * 1024, 2048ll * 2048);

  // 4. attn(f32) = e/den; inv_dens
  attn_norm<<<dim3(16384), 256, 0, stream>>>(e, partials, attn, inv_dens);

  // 5. PV: out_mid = (e @ vh) * inv_den[row]   (256², nbm=8, nbn=4)
  gemm2p<3><<<dim3(32, 8), 512, 0, stream>>>(e, vhT, out_mid, inv_dens,
      2048, 1024, 2048, 8, 4, 2048ll * 2048, 1024ll * 2048, 2048ll * 1024);

  // 6. FC: fc = out_mid @ Wfc  (256²)
  gemm2p<0><<<dim3(256, 1), 512, 0, stream>>>(out_mid, WfcT, fc, nullptr,
      16384, 1024, 1024, 64, 4, 0, 0, 0);

  // 7. out0 = LN(fc + q)
  if (qb_ws)
    ln_kernel<true><<<dim3(16384), 256, 0, stream>>>(fc, qb, gamma, beta, out0);
  else
    ln_kernel<false><<<dim3(16384), 256, 0, stream>>>(fc, q, gamma, beta, out0);
}